// Round 2
// baseline (486.966 us; speedup 1.0000x reference)
//
#include <hip/hip_runtime.h>
#include <math.h>

// Morphological dilation, k=4x4, TF SAME padding (pad top/left=1, bottom/right=2).
// x: (8, 512, 512, 32) fp32 NHWC;  w: (4, 4, 32) fp32;  out: same as x.
// out[b,y,x,c] = max_{i,j} x[b, y+i-1, x+j-1, c] + w[i,j,c]  (OOB -> -inf)

constexpr int H = 512;
constexpr int W = 512;
constexpr int C = 32;
constexpr int T = 8;   // output rows per thread (y-strip)

__device__ __forceinline__ float4 fmax4(float4 a, float4 b) {
    return make_float4(fmaxf(a.x, b.x), fmaxf(a.y, b.y),
                       fmaxf(a.z, b.z), fmaxf(a.w, b.w));
}
__device__ __forceinline__ float4 fadd4(float4 a, float4 b) {
    return make_float4(a.x + b.x, a.y + b.y, a.z + b.z, a.w + b.w);
}
__device__ __forceinline__ float4 sel4(bool ok, float4 v) {
    const float NI = -INFINITY;
    return make_float4(ok ? v.x : NI, ok ? v.y : NI,
                       ok ? v.z : NI, ok ? v.w : NI);
}

// xb: batch base already offset by this thread's channel quad (c4).
// Branch-free (for YCHK=XCHK=false, pure straight-line) strip body.
template<bool YCHK, bool XCHK>
__device__ __forceinline__ void dil_body(const float* __restrict__ xb,
                                         const float4 wv[16],
                                         float4 acc[T],
                                         const int y0, const int xp) {
#pragma unroll
    for (int r = 0; r < T + 3; ++r) {
        int yy = y0 - 1 + r;
        bool yok = true;
        if (YCHK) {
            yok = (yy >= 0) & (yy < H);
            yy = min(max(yy, 0), H - 1);    // safe clamped address
        }
        const float* rowp = xb + (size_t)yy * (W * C);

        float4 px[4];
#pragma unroll
        for (int j = 0; j < 4; ++j) {
            int xx = xp + j - 1;
            bool ok = yok;
            if (XCHK) {
                ok = ok & (xx >= 0) & (xx < W);
                xx = min(max(xx, 0), W - 1);
            }
            float4 v = *reinterpret_cast<const float4*>(rowp + (size_t)xx * C);
            px[j] = (YCHK || XCHK) ? sel4(ok, v) : v;
        }

#pragma unroll
        for (int i = 0; i < 4; ++i) {
            const int t = r - i;            // unroll-constant: static acc index
            if (t < 0 || t >= T) continue;  // folded at compile time
            float4 v = fadd4(px[0], wv[i * 4 + 0]);
            v = fmax4(v, fadd4(px[1], wv[i * 4 + 1]));
            v = fmax4(v, fadd4(px[2], wv[i * 4 + 2]));
            v = fmax4(v, fadd4(px[3], wv[i * 4 + 3]));
            acc[t] = fmax4(acc[t], v);
        }
    }
}

__global__ __launch_bounds__(256, 4)   // 4 waves/EU min -> 128-VGPR cap: keeps wv[] resident
void dil2d_kernel(const float* __restrict__ xin,
                  const float* __restrict__ wt,
                  float* __restrict__ out) {
    // thread -> (channel-quad, x); block covers 32 x positions * 8 c-quads
    const int c4 = (threadIdx.x & 7) * 4;        // channel offset 0,4,...,28
    const int xl = threadIdx.x >> 3;             // 0..31
    const int xp = blockIdx.x * 32 + xl;         // 0..511
    const int y0 = blockIdx.y * T;               // strip start row
    const int b  = blockIdx.z;

    // hoist the 4x4 weight taps for our 4 channels into registers (64 VGPRs)
    float4 wv[16];
#pragma unroll
    for (int k = 0; k < 16; ++k)
        wv[k] = *reinterpret_cast<const float4*>(wt + k * C + c4);

    const float4 NEG = make_float4(-INFINITY, -INFINITY, -INFINITY, -INFINITY);
    float4 acc[T];
#pragma unroll
    for (int t = 0; t < T; ++t) acc[t] = NEG;

    const float* xb = xin + (size_t)b * H * W * C + c4;

    // wave-uniform edge classification: 85% of blocks take the pure
    // straight-line path with zero bounds logic.
    const bool yedge = (blockIdx.y == 0) || (blockIdx.y == gridDim.y - 1);
    const bool xedge = (blockIdx.x == 0) || (blockIdx.x == gridDim.x - 1);

    if (!yedge && !xedge)      dil_body<false, false>(xb, wv, acc, y0, xp);
    else if (yedge && !xedge)  dil_body<true,  false>(xb, wv, acc, y0, xp);
    else if (!yedge && xedge)  dil_body<false, true >(xb, wv, acc, y0, xp);
    else                       dil_body<true,  true >(xb, wv, acc, y0, xp);

    float* ob = out + (((size_t)b * H + y0) * W + xp) * C + c4;
#pragma unroll
    for (int t = 0; t < T; ++t)
        *reinterpret_cast<float4*>(ob + (size_t)t * W * C) = acc[t];
}

extern "C" void kernel_launch(void* const* d_in, const int* in_sizes, int n_in,
                              void* d_out, int out_size, void* d_ws, size_t ws_size,
                              hipStream_t stream) {
    const float* x = (const float*)d_in[0];
    const float* w = (const float*)d_in[1];
    float* o = (float*)d_out;

    dim3 block(256);
    dim3 grid(W * (C / 4) / 256,   // 16: x*cquad tiles
              H / T,               // 64: y strips
              8);                  // batch
    dil2d_kernel<<<grid, block, 0, stream>>>(x, w, o);
}

// Round 3
// 127.914 us; speedup vs baseline: 3.8070x; 3.8070x over previous
//
#include <hip/hip_runtime.h>
#include <math.h>

// Morphological dilation, k=4x4, TF SAME padding (pad top/left=1, bottom/right=2).
// x: (8, 512, 512, 32) fp32 NHWC;  w: (4, 4, 32) fp32;  out: same as x.
// out[b,y,x,c] = max_{i,j} x[b, y+i-1, x+j-1, c] + w[i,j,c]  (OOB -> -inf)
//
// Design notes (R1/R2 post-mortem): 64-VGPR tier is what the allocator gives
// a 256-thread block no matter what __launch_bounds__ asks for; float4-per-
// thread needed ~112 regs -> R1 reloaded weights in-loop (latency-bound),
// R2 spilled (990 MB scratch writes). This version is scalar-per-channel:
// ~40 VGPR true demand, weights resident, 11 independent loads/thread.

constexpr int H = 512;
constexpr int W = 512;
constexpr int C = 32;
constexpr int T = 8;   // output rows per thread (y-strip)

template<bool EDGE>
__device__ __forceinline__ void dil_body(const float* __restrict__ xb,
                                         const float wv[16],
                                         float acc[T],
                                         const int y0, const int xp) {
    const float NI = -INFINITY;
#pragma unroll
    for (int r = 0; r < T + 3; ++r) {
        int yy = y0 - 1 + r;
        bool yok = true;
        if (EDGE) {
            yok = ((unsigned)yy < (unsigned)H);
            yy = min(max(yy, 0), H - 1);          // safe clamped address
        }
        const float* rowp = xb + (size_t)yy * (W * C);

        float px[4];
#pragma unroll
        for (int j = 0; j < 4; ++j) {
            int xx = xp + j - 1;
            if (EDGE) {
                bool ok = yok & ((unsigned)xx < (unsigned)W);
                xx = min(max(xx, 0), W - 1);
                float v = rowp[(size_t)xx * C];
                px[j] = ok ? v : NI;
            } else {
                px[j] = rowp[(size_t)xx * C];
            }
        }

#pragma unroll
        for (int i = 0; i < 4; ++i) {
            const int t = r - i;            // unroll-constant: static acc index
            if (t < 0 || t >= T) continue;  // folded at compile time
            float v = fmaxf(fmaxf(px[0] + wv[i * 4 + 0], px[1] + wv[i * 4 + 1]),
                            fmaxf(px[2] + wv[i * 4 + 2], px[3] + wv[i * 4 + 3]));
            acc[t] = fmaxf(acc[t], v);
        }
    }
}

__global__ __launch_bounds__(256)
void dil2d_kernel(const float* __restrict__ xin,
                  const float* __restrict__ wt,
                  float* __restrict__ out) {
    // thread -> (channel, x): lanes walk c then x -> 256 B contiguous per wave load
    const int c  = threadIdx.x & (C - 1);        // 0..31
    const int xl = threadIdx.x >> 5;             // 0..7
    const int xp = blockIdx.x * 8 + xl;          // 0..511
    const int y0 = blockIdx.y * T;               // strip start row
    const int b  = blockIdx.z;

    // hoist the 4x4 weight taps for our channel into registers (16 VGPRs)
    float wv[16];
#pragma unroll
    for (int k = 0; k < 16; ++k)
        wv[k] = wt[k * C + c];

    float acc[T];
#pragma unroll
    for (int t = 0; t < T; ++t) acc[t] = -INFINITY;

    const float* xb = xin + (size_t)b * H * W * C + c;

    // wave-uniform edge classification: ~94% of blocks take the
    // zero-bounds-logic straight-line path.
    const bool yedge = (blockIdx.y == 0) || (blockIdx.y == gridDim.y - 1);
    const bool xedge = (blockIdx.x == 0) || (blockIdx.x == gridDim.x - 1);

    if (yedge | xedge) dil_body<true >(xb, wv, acc, y0, xp);
    else               dil_body<false>(xb, wv, acc, y0, xp);

    float* ob = out + (((size_t)b * H + y0) * W + xp) * C + c;
#pragma unroll
    for (int t = 0; t < T; ++t)
        ob[(size_t)t * W * C] = acc[t];
}

extern "C" void kernel_launch(void* const* d_in, const int* in_sizes, int n_in,
                              void* d_out, int out_size, void* d_ws, size_t ws_size,
                              hipStream_t stream) {
    const float* x = (const float*)d_in[0];
    const float* w = (const float*)d_in[1];
    float* o = (float*)d_out;

    dim3 block(256);
    dim3 grid(W / 8,    // 64: x tiles (8 x-positions per block)
              H / T,    // 64: y strips
              8);       // batch
    dil2d_kernel<<<grid, block, 0, stream>>>(x, w, o);
}

// Round 4
// 97.448 us; speedup vs baseline: 4.9972x; 1.3126x over previous
//
#include <hip/hip_runtime.h>
#include <math.h>

// Morphological dilation, k=4x4, TF SAME padding (pad top/left=1, bottom/right=2).
// x: (8, 512, 512, 32) fp32 NHWC;  w: (4, 4, 32) fp32;  out: same as x.
// out[b,y,x,c] = max_{i,j} x[b, y+i-1, x+j-1, c] + w[i,j,c]  (OOB -> -inf)
//
// R1/R2 lesson: 256-thread blocks get the 64-VGPR tier; keep true register
// demand under it (scalar-per-channel). R3: 128 µs with T=8.
// R4 changes: T=16 (y-halo 1.375x -> 1.19x) + nontemporal stores (don't let
// the 268 MB write stream evict the input working set from L2/L3).

constexpr int H = 512;
constexpr int W = 512;
constexpr int C = 32;
constexpr int T = 16;  // output rows per thread (y-strip)

template<bool EDGE>
__device__ __forceinline__ void dil_body(const float* __restrict__ xb,
                                         const float wv[16],
                                         float acc[T],
                                         const int y0, const int xp) {
    const float NI = -INFINITY;
#pragma unroll
    for (int r = 0; r < T + 3; ++r) {
        int yy = y0 - 1 + r;
        bool yok = true;
        if (EDGE) {
            yok = ((unsigned)yy < (unsigned)H);
            yy = min(max(yy, 0), H - 1);          // safe clamped address
        }
        const float* rowp = xb + (size_t)yy * (W * C);

        float px[4];
#pragma unroll
        for (int j = 0; j < 4; ++j) {
            int xx = xp + j - 1;
            if (EDGE) {
                bool ok = yok & ((unsigned)xx < (unsigned)W);
                xx = min(max(xx, 0), W - 1);
                float v = rowp[(size_t)xx * C];
                px[j] = ok ? v : NI;
            } else {
                px[j] = rowp[(size_t)xx * C];
            }
        }

#pragma unroll
        for (int i = 0; i < 4; ++i) {
            const int t = r - i;            // unroll-constant: static acc index
            if (t < 0 || t >= T) continue;  // folded at compile time
            float v = fmaxf(fmaxf(px[0] + wv[i * 4 + 0], px[1] + wv[i * 4 + 1]),
                            fmaxf(px[2] + wv[i * 4 + 2], px[3] + wv[i * 4 + 3]));
            acc[t] = fmaxf(acc[t], v);
        }
    }
}

__global__ __launch_bounds__(256)
void dil2d_kernel(const float* __restrict__ xin,
                  const float* __restrict__ wt,
                  float* __restrict__ out) {
    // thread -> (channel, x): lanes walk c then x -> 256 B contiguous per wave load
    const int c  = threadIdx.x & (C - 1);        // 0..31
    const int xl = threadIdx.x >> 5;             // 0..7
    const int xp = blockIdx.x * 8 + xl;          // 0..511
    const int y0 = blockIdx.y * T;               // strip start row
    const int b  = blockIdx.z;

    // hoist the 4x4 weight taps for our channel into registers (16 VGPRs)
    float wv[16];
#pragma unroll
    for (int k = 0; k < 16; ++k)
        wv[k] = wt[k * C + c];

    float acc[T];
#pragma unroll
    for (int t = 0; t < T; ++t) acc[t] = -INFINITY;

    const float* xb = xin + (size_t)b * H * W * C + c;

    // wave-uniform edge classification: 58/64 x-tiles x 30/32 y-strips take
    // the zero-bounds-logic straight-line path.
    const bool yedge = (blockIdx.y == 0) || (blockIdx.y == gridDim.y - 1);
    const bool xedge = (blockIdx.x == 0) || (blockIdx.x == gridDim.x - 1);

    if (yedge | xedge) dil_body<true >(xb, wv, acc, y0, xp);
    else               dil_body<false>(xb, wv, acc, y0, xp);

    float* ob = out + (((size_t)b * H + y0) * W + xp) * C + c;
#pragma unroll
    for (int t = 0; t < T; ++t)
        __builtin_nontemporal_store(acc[t], ob + (size_t)t * W * C);
}

extern "C" void kernel_launch(void* const* d_in, const int* in_sizes, int n_in,
                              void* d_out, int out_size, void* d_ws, size_t ws_size,
                              hipStream_t stream) {
    const float* x = (const float*)d_in[0];
    const float* w = (const float*)d_in[1];
    float* o = (float*)d_out;

    dim3 block(256);
    dim3 grid(W / 8,    // 64: x tiles (8 x-positions per block)
              H / T,    // 32: y strips
              8);       // batch
    dil2d_kernel<<<grid, block, 0, stream>>>(x, w, o);
}